// Round 5
// baseline (4315.918 us; speedup 1.0000x reference)
//
#include <hip/hip_runtime.h>

#define B_  4
#define C_  256
#define N_  4096
#define C8_ 32
#define C2_ 128

// ---------------------------------------------------------------------------
// dst[b][o][n] = bias[o] + sum_c w[o][c] * x[b][c][n]      (naive, f32)
// one thread per output element; idx = (b*OC + o)*N + n
// ---------------------------------------------------------------------------
__global__ __launch_bounds__(256) void lin_naive(
    const float* __restrict__ x, const float* __restrict__ w,
    const float* __restrict__ bias, float* __restrict__ dst, int OC) {
    long idx = (long)blockIdx.x * 256 + threadIdx.x;
    long total = (long)B_ * OC * N_;
    if (idx >= total) return;
    int n = (int)(idx & (N_ - 1));
    int o = (int)((idx >> 12) % OC);
    int b = (int)(idx / ((long)OC * N_));
    float acc = bias[o];
    const float* xb = x + (long)b * C_ * N_ + n;
    const float* wr = w + (long)o * C_;
    for (int c = 0; c < C_; ++c) acc += wr[c] * xb[(long)c * N_];
    dst[idx] = acc;
}

// ---------------------------------------------------------------------------
// One block per (n, b): scores row -> softmax -> PV.   (naive, f32)
// theta/phi: [b][32][N], g: [b][128][N], out_v: [b][n][c] f32
// ---------------------------------------------------------------------------
__global__ __launch_bounds__(256) void attn_naive(
    const float* __restrict__ theta, const float* __restrict__ phi,
    const float* __restrict__ g, float* __restrict__ out_v) {
    __shared__ __align__(16) float sm[N_];   // 16 KB score row
    __shared__ float red[256];
    __shared__ float th[C8_];
    const int t = threadIdx.x;
    const int n = blockIdx.x;
    const int b = blockIdx.y;

    if (t < C8_) th[t] = theta[((long)b * C8_ + t) * N_ + n];
    __syncthreads();

    // pass 1: scores + local max
    float lmax = -1e30f;
    for (int m = t; m < N_; m += 256) {
        float s = 0.f;
#pragma unroll 8
        for (int o = 0; o < C8_; ++o)
            s += th[o] * phi[((long)b * C8_ + o) * N_ + m];
        sm[m] = s;
        lmax = fmaxf(lmax, s);
    }
    red[t] = lmax;
    __syncthreads();
    for (int st = 128; st >= 1; st >>= 1) {
        if (t < st) red[t] = fmaxf(red[t], red[t + st]);
        __syncthreads();
    }
    const float gmax = red[0];
    __syncthreads();                 // red about to be reused

    // pass 2: exp + local sum
    float lsum = 0.f;
    for (int m = t; m < N_; m += 256) {
        float p = __expf(sm[m] - gmax);
        sm[m] = p;
        lsum += p;
    }
    red[t] = lsum;
    __syncthreads();
    for (int st = 128; st >= 1; st >>= 1) {
        if (t < st) red[t] += red[t + st];
        __syncthreads();
    }
    const float inv = 1.0f / red[0];

    // pass 3: PV — threads 0..127 each own one channel c
    if (t < C2_) {
        const float4* gr = (const float4*)(g + ((long)b * C2_ + t) * N_);
        const float4* pm = (const float4*)sm;
        float acc = 0.f;
        for (int m4 = 0; m4 < N_ / 4; ++m4) {
            float4 gv = gr[m4];
            float4 pv = pm[m4];
            acc += pv.x * gv.x + pv.y * gv.y + pv.z * gv.z + pv.w * gv.w;
        }
        out_v[((long)b * N_ + n) * C2_ + t] = acc * inv;
    }
}

// ---------------------------------------------------------------------------
// out[b][o][n] = b_o[o] + sum_c w_o[o][c]*out_v[b][n][c] + x[b][o][n]
// one thread per output element.
// ---------------------------------------------------------------------------
__global__ __launch_bounds__(256) void outproj_naive(
    const float* __restrict__ out_v, const float* __restrict__ wo,
    const float* __restrict__ bo, const float* __restrict__ x,
    float* __restrict__ out) {
    long idx = (long)blockIdx.x * 256 + threadIdx.x;
    if (idx >= (long)B_ * C_ * N_) return;
    int n = (int)(idx & (N_ - 1));
    int o = (int)((idx >> 12) & 255);
    int b = (int)(idx >> 20);
    const float4* ov = (const float4*)(out_v + ((long)b * N_ + n) * C2_);
    const float4* wr = (const float4*)(wo + (long)o * C2_);
    float acc = bo[o];
    for (int c4 = 0; c4 < C2_ / 4; ++c4) {
        float4 a = ov[c4];
        float4 w = wr[c4];
        acc += a.x * w.x + a.y * w.y + a.z * w.z + a.w * w.w;
    }
    out[idx] = acc + x[idx];
}

// ---------------------------------------------------------------------------
extern "C" void kernel_launch(void* const* d_in, const int* in_sizes, int n_in,
                              void* d_out, int out_size, void* d_ws, size_t ws_size,
                              hipStream_t stream) {
    const float* x  = (const float*)d_in[0];
    const float* wt = (const float*)d_in[1];
    const float* bt = (const float*)d_in[2];
    const float* wp = (const float*)d_in[3];
    const float* bp = (const float*)d_in[4];
    const float* wg = (const float*)d_in[5];
    const float* bg = (const float*)d_in[6];
    const float* wo = (const float*)d_in[7];
    const float* bo = (const float*)d_in[8];

    // ws: theta 2MB | phi 2MB | out_v 8MB   (12 MB total)
    // g (8MB f32) lives in d_out's first half; overwritten by outproj after use.
    char* ws = (char*)d_ws;
    float* theta = (float*)(ws);
    float* phi   = (float*)(ws + (2u << 20));
    float* ov    = (float*)(ws + (4u << 20));
    float* g     = (float*)d_out;

    lin_naive<<<dim3(2048), dim3(256), 0, stream>>>(x, wt, bt, theta, 32);
    lin_naive<<<dim3(2048), dim3(256), 0, stream>>>(x, wp, bp, phi, 32);
    lin_naive<<<dim3(8192), dim3(256), 0, stream>>>(x, wg, bg, g, 128);
    attn_naive<<<dim3(N_, B_), dim3(256), 0, stream>>>(theta, phi, g, ov);
    outproj_naive<<<dim3(16384), dim3(256), 0, stream>>>(ov, wo, bo, x, (float*)d_out);
}

// Round 6
// 909.871 us; speedup vs baseline: 4.7434x; 4.7434x over previous
//
#include <hip/hip_runtime.h>

#define B_  4
#define C_  256
#define N_  4096
#define C8_ 32
#define C2_ 128
#define NN  4096
#define BM  128
#define BQ  32

typedef unsigned int uint32;

__device__ __forceinline__ uint32 rne16(float x) {
    uint32 b = __float_as_uint(x);
    return (b + 0x7fffu + ((b >> 16) & 1u)) >> 16;
}

// ---------------------------------------------------------------------------
// dst[b][o][n] = bias[o] + sum_c w[o][c] * x[b][c][n]      (naive, f32)
// ---------------------------------------------------------------------------
__global__ __launch_bounds__(256) void lin_naive(
    const float* __restrict__ x, const float* __restrict__ w,
    const float* __restrict__ bias, float* __restrict__ dst, int OC) {
    long idx = (long)blockIdx.x * 256 + threadIdx.x;
    long total = (long)B_ * OC * N_;
    if (idx >= total) return;
    int n = (int)(idx & (N_ - 1));
    int o = (int)((idx >> 12) % OC);
    int b = (int)(idx / ((long)OC * N_));
    float acc = bias[o];
    const float* xb = x + (long)b * C_ * N_ + n;
    const float* wr = w + (long)o * C_;
    for (int c = 0; c < C_; ++c) acc += wr[c] * xb[(long)c * N_];
    dst[idx] = acc;
}

// ---------------------------------------------------------------------------
// Transpose g [b][c][n] f32 -> g_t [b][n][c] bf16
// ---------------------------------------------------------------------------
__global__ __launch_bounds__(256) void transp_g(
    const float* __restrict__ g, unsigned short* __restrict__ g_t) {
    __shared__ float tile[32][33];
    const int b  = blockIdx.z;
    const int c0 = blockIdx.y * 32;
    const int n0 = blockIdx.x * 32;
    const int tx = threadIdx.x & 31;
    const int ty = threadIdx.x >> 5;          // 0..7
#pragma unroll
    for (int i = 0; i < 32; i += 8)
        tile[ty + i][tx] = g[((long)b * C2_ + c0 + ty + i) * N_ + n0 + tx];
    __syncthreads();
#pragma unroll
    for (int i = 0; i < 32; i += 8)
        g_t[((long)b * N_ + n0 + ty + i) * C2_ + c0 + tx] =
            (unsigned short)rne16(tile[tx][ty + i]);
}

// ---------------------------------------------------------------------------
// Flash attention: out_v[b][n][c] = softmax_m(theta.phi) @ g^T   (fp32 VALU)
// grid (128, 4), 256 threads. BQ=32 rows, BM=128 key tile. out_v f32.
// ---------------------------------------------------------------------------
__global__ __launch_bounds__(256, 2) void flash_kernel(
    const float* __restrict__ theta_t, const float* __restrict__ phi,
    const unsigned short* __restrict__ g_t, float* __restrict__ out_v) {
    __shared__ __align__(16) float th[32 * 32];            // [o][r]
    __shared__ __align__(16) unsigned short gls[BM * 128]; // [m][c] bf16
    __shared__ float pls[BM * 33];                         // [m][r] pad

    const int t  = threadIdx.x;
    const int b  = blockIdx.y;
    const int n0 = blockIdx.x * BQ;
    const int rg = t >> 5;        // 0..7  (4 rows each)
    const int mg = t & 31;
    const int r0 = rg * 4;
    const int m0 = mg * 4;        // phase A cols
    const int c0 = mg * 4;        // phase B channels

    {   // stage theta tile [32 o][32 r]
        int o = t >> 3, r4 = (t & 7) * 4;
        *(float4*)&th[o * 32 + r4] =
            *(const float4*)&theta_t[(size_t)(b * 32 + o) * NN + n0 + r4];
    }

    float acc[4][4];
#pragma unroll
    for (int i = 0; i < 4; ++i)
#pragma unroll
        for (int j = 0; j < 4; ++j) acc[i][j] = 0.f;
    float mx[4], l[4];
#pragma unroll
    for (int i = 0; i < 4; ++i) { mx[i] = -1e30f; l[i] = 0.f; }

    const float* phib = phi + (size_t)b * 32 * NN;
    const unsigned short* gb = g_t + (size_t)b * NN * 128;
    __syncthreads();

    for (int mt = 0; mt < NN; mt += BM) {
        // ---- stage g tile [128 m][128 c] bf16 (straight copy, coalesced) ----
#pragma unroll
        for (int j = 0; j < 8; ++j) {
            int chunk = j * 256 + t;   // 16B chunks
            *(uint4*)&gls[chunk * 8] = *(const uint4*)&gb[(size_t)mt * 128 + chunk * 8];
        }

        // ---- phase A: scores s[4 rows][4 cols] ----
        float s[4][4];
#pragma unroll
        for (int i = 0; i < 4; ++i)
#pragma unroll
            for (int j = 0; j < 4; ++j) s[i][j] = 0.f;
#pragma unroll 4
        for (int o = 0; o < 32; ++o) {
            const float4 tv = *(const float4*)&th[o * 32 + r0];
            const float4 pv = *(const float4*)&phib[(size_t)o * NN + mt + m0];
            s[0][0] += tv.x * pv.x; s[0][1] += tv.x * pv.y; s[0][2] += tv.x * pv.z; s[0][3] += tv.x * pv.w;
            s[1][0] += tv.y * pv.x; s[1][1] += tv.y * pv.y; s[1][2] += tv.y * pv.z; s[1][3] += tv.y * pv.w;
            s[2][0] += tv.z * pv.x; s[2][1] += tv.z * pv.y; s[2][2] += tv.z * pv.z; s[2][3] += tv.z * pv.w;
            s[3][0] += tv.w * pv.x; s[3][1] += tv.w * pv.y; s[3][2] += tv.w * pv.z; s[3][3] += tv.w * pv.w;
        }

        // ---- online softmax over the 32 mg-lanes (each holds 4 m) ----
        float rmx[4], nm[4], scl[4], rs[4], p[4][4];
#pragma unroll
        for (int i = 0; i < 4; ++i)
            rmx[i] = fmaxf(fmaxf(s[i][0], s[i][1]), fmaxf(s[i][2], s[i][3]));
#pragma unroll
        for (int off = 16; off >= 1; off >>= 1)
#pragma unroll
            for (int i = 0; i < 4; ++i)
                rmx[i] = fmaxf(rmx[i], __shfl_xor(rmx[i], off, 32));
#pragma unroll
        for (int i = 0; i < 4; ++i) {
            nm[i]  = fmaxf(mx[i], rmx[i]);
            scl[i] = __expf(mx[i] - nm[i]);
            rs[i]  = 0.f;
#pragma unroll
            for (int j = 0; j < 4; ++j) {
                p[i][j] = __expf(s[i][j] - nm[i]);
                rs[i] += p[i][j];
            }
        }
#pragma unroll
        for (int off = 16; off >= 1; off >>= 1)
#pragma unroll
            for (int i = 0; i < 4; ++i)
                rs[i] += __shfl_xor(rs[i], off, 32);
#pragma unroll
        for (int i = 0; i < 4; ++i) {
            l[i] = l[i] * scl[i] + rs[i];
            mx[i] = nm[i];
        }
#pragma unroll
        for (int i = 0; i < 4; ++i)
#pragma unroll
            for (int j = 0; j < 4; ++j)
                pls[(m0 + j) * 33 + r0 + i] = p[i][j];
        __syncthreads();

        // ---- phase B: rescale + PV accumulate (scl is rg-group-uniform) ----
#pragma unroll
        for (int i = 0; i < 4; ++i) {
            acc[i][0] *= scl[i]; acc[i][1] *= scl[i];
            acc[i][2] *= scl[i]; acc[i][3] *= scl[i];
        }
#pragma unroll 4
        for (int m = 0; m < BM; ++m) {
            uint2 gv = *(const uint2*)&gls[m * 128 + c0];
            float g0 = __uint_as_float(gv.x << 16);
            float g1 = __uint_as_float(gv.x & 0xffff0000u);
            float g2 = __uint_as_float(gv.y << 16);
            float g3 = __uint_as_float(gv.y & 0xffff0000u);
#pragma unroll
            for (int i = 0; i < 4; ++i) {
                float pv = pls[m * 33 + r0 + i];
                acc[i][0] += pv * g0; acc[i][1] += pv * g1;
                acc[i][2] += pv * g2; acc[i][3] += pv * g3;
            }
        }
        __syncthreads();
    }

#pragma unroll
    for (int i = 0; i < 4; ++i) {
        const float inv = 1.0f / l[i];
        *(float4*)&out_v[((size_t)b * NN + n0 + r0 + i) * 128 + c0] =
            make_float4(acc[i][0] * inv, acc[i][1] * inv,
                        acc[i][2] * inv, acc[i][3] * inv);
    }
}

// ---------------------------------------------------------------------------
// out[b][o][n] = b_o[o] + sum_c w_o[o][c]*out_v[b][n][c] + x[b][o][n]
// ---------------------------------------------------------------------------
__global__ __launch_bounds__(256) void outproj_naive(
    const float* __restrict__ out_v, const float* __restrict__ wo,
    const float* __restrict__ bo, const float* __restrict__ x,
    float* __restrict__ out) {
    long idx = (long)blockIdx.x * 256 + threadIdx.x;
    if (idx >= (long)B_ * C_ * N_) return;
    int n = (int)(idx & (N_ - 1));
    int o = (int)((idx >> 12) & 255);
    int b = (int)(idx >> 20);
    const float4* ov = (const float4*)(out_v + ((long)b * N_ + n) * C2_);
    const float4* wr = (const float4*)(wo + (long)o * C2_);
    float acc = bo[o];
    for (int c4 = 0; c4 < C2_ / 4; ++c4) {
        float4 a = ov[c4];
        float4 w = wr[c4];
        acc += a.x * w.x + a.y * w.y + a.z * w.z + a.w * w.w;
    }
    out[idx] = acc + x[idx];
}

// ---------------------------------------------------------------------------
extern "C" void kernel_launch(void* const* d_in, const int* in_sizes, int n_in,
                              void* d_out, int out_size, void* d_ws, size_t ws_size,
                              hipStream_t stream) {
    const float* x  = (const float*)d_in[0];
    const float* wt = (const float*)d_in[1];
    const float* bt = (const float*)d_in[2];
    const float* wp = (const float*)d_in[3];
    const float* bp = (const float*)d_in[4];
    const float* wg = (const float*)d_in[5];
    const float* bg = (const float*)d_in[6];
    const float* wo = (const float*)d_in[7];
    const float* bo = (const float*)d_in[8];

    // ws: theta 2MB | phi 2MB | out_v 8MB = 12.0 MB (same as passing naive run)
    char* ws = (char*)d_ws;
    float* theta = (float*)(ws);
    float* phi   = (float*)(ws + (2u << 20));
    float* ov    = (float*)(ws + (4u << 20));
    // d_out scratch: g f32 [b][c][n] 8MB | g_t bf16 [b][n][c] 4MB (dead before outproj writes)
    float* g            = (float*)d_out;
    unsigned short* g_t = (unsigned short*)((char*)d_out + (8u << 20));

    lin_naive<<<dim3(2048), dim3(256), 0, stream>>>(x, wt, bt, theta, 32);
    lin_naive<<<dim3(2048), dim3(256), 0, stream>>>(x, wp, bp, phi, 32);
    lin_naive<<<dim3(8192), dim3(256), 0, stream>>>(x, wg, bg, g, 128);
    transp_g<<<dim3(128, 4, 4), dim3(256), 0, stream>>>(g, g_t);
    flash_kernel<<<dim3(128, 4), dim3(256), 0, stream>>>(theta, phi, g_t, ov);
    outproj_naive<<<dim3(16384), dim3(256), 0, stream>>>(ov, wo, bo, x, (float*)d_out);
}

// Round 11
// 649.272 us; speedup vs baseline: 6.6473x; 1.4014x over previous
//
#include <hip/hip_runtime.h>

#define B_  4
#define C_  256
#define N_  4096
#define C8_ 32
#define C2_ 128

typedef unsigned int uint32;
typedef __bf16 bf16x8 __attribute__((ext_vector_type(8)));
typedef float f32x4 __attribute__((ext_vector_type(4)));

// ---------------------------------------------------------------------------
// dst[b][o][n] = bias[o] + sum_c w[o][c] * x[b][c][n]      (naive, f32)
// (verified round 5/6)
// ---------------------------------------------------------------------------
__global__ __launch_bounds__(256) void lin_naive(
    const float* __restrict__ x, const float* __restrict__ w,
    const float* __restrict__ bias, float* __restrict__ dst, int OC) {
    long idx = (long)blockIdx.x * 256 + threadIdx.x;
    long total = (long)B_ * OC * N_;
    if (idx >= total) return;
    int n = (int)(idx & (N_ - 1));
    int o = (int)((idx >> 12) % OC);
    int b = (int)(idx / ((long)OC * N_));
    float acc = bias[o];
    const float* xb = x + (long)b * C_ * N_ + n;
    const float* wr = w + (long)o * C_;
    for (int c = 0; c < C_; ++c) acc += wr[c] * xb[(long)c * N_];
    dst[idx] = acc;
}

// ---------------------------------------------------------------------------
// Elementwise cast g f32 [b][c][n] -> gT bf16 (same layout = V^T for MFMA)
// grid 2048 x 256 threads x 4 elems = 2,097,152 = B*C2*N exactly.
// (round-10 crash: this grid was 8192 -> 4x OOB past d_out; fixed)
// ---------------------------------------------------------------------------
__global__ __launch_bounds__(256) void cast_g(
    const float* __restrict__ g, __bf16* __restrict__ gT) {
    long i = ((long)blockIdx.x * 256 + threadIdx.x) * 4;
    const float4 v = *(const float4*)&g[i];
    gT[i + 0] = (__bf16)v.x;
    gT[i + 1] = (__bf16)v.y;
    gT[i + 2] = (__bf16)v.z;
    gT[i + 3] = (__bf16)v.w;
}

// ---------------------------------------------------------------------------
// Transpose phi f32 [b][32][N] -> phiT bf16 [b][N][32]
// (structural clone of verified transp_g, 32 channels)
// ---------------------------------------------------------------------------
__global__ __launch_bounds__(256) void transp_phi(
    const float* __restrict__ phi, __bf16* __restrict__ phiT) {
    __shared__ float tile[32][33];
    const int b  = blockIdx.y;
    const int n0 = blockIdx.x * 32;
    const int tx = threadIdx.x & 31;
    const int ty = threadIdx.x >> 5;          // 0..7
#pragma unroll
    for (int i = 0; i < 32; i += 8)
        tile[ty + i][tx] = phi[((long)b * C8_ + ty + i) * N_ + n0 + tx];
    __syncthreads();
#pragma unroll
    for (int i = 0; i < 32; i += 8)
        phiT[((long)b * N_ + n0 + ty + i) * C8_ + tx] = (__bf16)tile[tx][ty + i];
}

// ---------------------------------------------------------------------------
// MFMA flash attention.
// grid (128, 4), 128 threads (2 waves). Wave w owns q-rows n0+w*16 .. +15.
// theta_t f32 [b][32][N]; phiT bf16 [b][N][32]; gT bf16 [b][128][N].
// out_v f32 [b][n][128].
// Fragment layouts (mfma_f32_16x16x32_bf16):
//   A: row=l&15, k=(l>>4)*8+j  |  B: col=l&15, k=(l>>4)*8+j
//   C/D: col=l&15, row=(l>>4)*4+reg      [m89/m91 verified]
// ---------------------------------------------------------------------------
__global__ __launch_bounds__(128, 2) void mfma_flash(
    const float* __restrict__ theta_t, const __bf16* __restrict__ phiT,
    const __bf16* __restrict__ gT, float* __restrict__ out_v) {
    __shared__ __align__(16) __bf16 phT[128 * 40];   // [m][o pad40]
    __shared__ __align__(16) __bf16 vT[128 * 136];   // [c][m pad136]
    __shared__ __align__(16) __bf16 pls[32 * 136];   // [n][m pad136]

    const int t   = threadIdx.x;
    const int b   = blockIdx.y;
    const int n0  = blockIdx.x * 32;
    const int w   = t >> 6;          // wave 0/1
    const int l   = t & 63;
    const int l15 = l & 15;
    const int lq  = l >> 4;          // 0..3

    // theta A fragment: A[row = l15][k = lq*8+j], rows = this wave's strip
    bf16x8 aq;
#pragma unroll
    for (int j = 0; j < 8; ++j)
        aq[j] = (__bf16)theta_t[(size_t)(b * C8_ + lq * 8 + j) * N_ + n0 + w * 16 + l15];

    f32x4 acc[8];
#pragma unroll
    for (int cf = 0; cf < 8; ++cf) acc[cf] = (f32x4){0.f, 0.f, 0.f, 0.f};
    float mx[4], ln[4];
#pragma unroll
    for (int r = 0; r < 4; ++r) { mx[r] = -1e30f; ln[r] = 0.f; }

    const f32x4 zero = {0.f, 0.f, 0.f, 0.f};

    for (int mt = 0; mt < N_; mt += 128) {
        __syncthreads();   // prev tile's LDS reads done
        {   // stage phT: thread t -> key row m=t (32 bf16 = 4×uint4)
            const uint4* src = (const uint4*)&phiT[((size_t)b * N_ + mt + t) * C8_];
            uint4* dst = (uint4*)&phT[t * 40];
#pragma unroll
            for (int j = 0; j < 4; ++j) dst[j] = src[j];
        }
        {   // stage vT: thread t -> channel row c=t (128 bf16 = 16×uint4)
            const uint4* src = (const uint4*)&gT[((size_t)b * C2_ + t) * N_ + mt];
            uint4* dst = (uint4*)&vT[t * 136];
#pragma unroll
            for (int j = 0; j < 16; ++j) dst[j] = src[j];
        }
        __syncthreads();

        // ---- QK: scores strip [16 n][128 m] = 8 mfma ----
        f32x4 s[8];
#pragma unroll
        for (int mf = 0; mf < 8; ++mf) {
            bf16x8 bk = *(const bf16x8*)&phT[(mf * 16 + l15) * 40 + lq * 8];
            s[mf] = __builtin_amdgcn_mfma_f32_16x16x32_bf16(aq, bk, zero, 0, 0, 0);
        }

        // ---- online softmax (rows = lq*4+reg, intra-16-lane-group) ----
        float rm[4], nm[4], scl[4], rs[4];
#pragma unroll
        for (int r = 0; r < 4; ++r) {
            rm[r] = s[0][r];
#pragma unroll
            for (int mf = 1; mf < 8; ++mf) rm[r] = fmaxf(rm[r], s[mf][r]);
        }
#pragma unroll
        for (int off = 8; off >= 1; off >>= 1)
#pragma unroll
            for (int r = 0; r < 4; ++r)
                rm[r] = fmaxf(rm[r], __shfl_xor(rm[r], off));
#pragma unroll
        for (int r = 0; r < 4; ++r) {
            nm[r]  = fmaxf(mx[r], rm[r]);
            scl[r] = __expf(mx[r] - nm[r]);
            rs[r]  = 0.f;
        }
#pragma unroll
        for (int mf = 0; mf < 8; ++mf)
#pragma unroll
            for (int r = 0; r < 4; ++r) {
                float p = __expf(s[mf][r] - nm[r]);
                s[mf][r] = p;
                rs[r] += p;
            }
#pragma unroll
        for (int off = 8; off >= 1; off >>= 1)
#pragma unroll
            for (int r = 0; r < 4; ++r)
                rs[r] += __shfl_xor(rs[r], off);
#pragma unroll
        for (int r = 0; r < 4; ++r) {
            ln[r] = ln[r] * scl[r] + rs[r];
            mx[r] = nm[r];
        }

        // ---- P -> LDS bf16 (own wave strip only) ----
#pragma unroll
        for (int mf = 0; mf < 8; ++mf)
#pragma unroll
            for (int r = 0; r < 4; ++r)
                pls[(w * 16 + lq * 4 + r) * 136 + mf * 16 + l15] = (__bf16)s[mf][r];
        __syncthreads();   // cross-lane LDS safety before A-frag reads

        // ---- rescale + PV: 4 msteps × 8 cfrags ----
#pragma unroll
        for (int cf = 0; cf < 8; ++cf)
#pragma unroll
            for (int r = 0; r < 4; ++r) acc[cf][r] *= scl[r];
#pragma unroll
        for (int ms = 0; ms < 4; ++ms) {
            bf16x8 ap = *(const bf16x8*)&pls[(w * 16 + l15) * 136 + ms * 32 + lq * 8];
#pragma unroll
            for (int cf = 0; cf < 8; ++cf) {
                bf16x8 bv = *(const bf16x8*)&vT[(cf * 16 + l15) * 136 + ms * 32 + lq * 8];
                acc[cf] = __builtin_amdgcn_mfma_f32_16x16x32_bf16(ap, bv, acc[cf], 0, 0, 0);
            }
        }
    }

    // ---- write out_v [b][n][c] f32 ----
    float inv[4];
#pragma unroll
    for (int r = 0; r < 4; ++r) inv[r] = 1.0f / ln[r];
#pragma unroll
    for (int cf = 0; cf < 8; ++cf)
#pragma unroll
        for (int r = 0; r < 4; ++r)
            out_v[((size_t)b * N_ + n0 + w * 16 + lq * 4 + r) * C2_ + cf * 16 + l15] =
                acc[cf][r] * inv[r];
}

// ---------------------------------------------------------------------------
// out[b][o][n] = b_o[o] + sum_c w_o[o][c]*out_v[b][n][c] + x[b][o][n]
// (verified round 5/6)
// ---------------------------------------------------------------------------
__global__ __launch_bounds__(256) void outproj_naive(
    const float* __restrict__ out_v, const float* __restrict__ wo,
    const float* __restrict__ bo, const float* __restrict__ x,
    float* __restrict__ out) {
    long idx = (long)blockIdx.x * 256 + threadIdx.x;
    if (idx >= (long)B_ * C_ * N_) return;
    int n = (int)(idx & (N_ - 1));
    int o = (int)((idx >> 12) & 255);
    int b = (int)(idx >> 20);
    const float4* ov = (const float4*)(out_v + ((long)b * N_ + n) * C2_);
    const float4* wr = (const float4*)(wo + (long)o * C2_);
    float acc = bo[o];
    for (int c4 = 0; c4 < C2_ / 4; ++c4) {
        float4 a = ov[c4];
        float4 w = wr[c4];
        acc += a.x * w.x + a.y * w.y + a.z * w.z + a.w * w.w;
    }
    out[idx] = acc + x[idx];
}

// ---------------------------------------------------------------------------
extern "C" void kernel_launch(void* const* d_in, const int* in_sizes, int n_in,
                              void* d_out, int out_size, void* d_ws, size_t ws_size,
                              hipStream_t stream) {
    const float* x  = (const float*)d_in[0];
    const float* wt = (const float*)d_in[1];
    const float* bt = (const float*)d_in[2];
    const float* wp = (const float*)d_in[3];
    const float* bp = (const float*)d_in[4];
    const float* wg = (const float*)d_in[5];
    const float* bg = (const float*)d_in[6];
    const float* wo = (const float*)d_in[7];
    const float* bo = (const float*)d_in[8];

    // ws: theta 2MB | phi 2MB | out_v f32 8MB = 12.0 MB (proven-safe footprint)
    char* ws = (char*)d_ws;
    float* theta = (float*)(ws);
    float* phi   = (float*)(ws + (2u << 20));
    float* ov    = (float*)(ws + (4u << 20));
    // d_out scratch (all dead before outproj_naive overwrites d_out):
    //   g f32 [b][128][N] 8MB | gT bf16 4MB | phiT bf16 1MB
    float*  g    = (float*)d_out;
    __bf16* gT   = (__bf16*)((char*)d_out + (8u << 20));
    __bf16* phiT = (__bf16*)((char*)d_out + (12u << 20));

    lin_naive<<<dim3(2048), dim3(256), 0, stream>>>(x, wt, bt, theta, 32);
    lin_naive<<<dim3(2048), dim3(256), 0, stream>>>(x, wp, bp, phi, 32);
    lin_naive<<<dim3(8192), dim3(256), 0, stream>>>(x, wg, bg, g, 128);
    cast_g<<<dim3(2048), dim3(256), 0, stream>>>(g, gT);
    transp_phi<<<dim3(128, 4), dim3(256), 0, stream>>>(phi, phiT);
    mfma_flash<<<dim3(128, 4), dim3(128), 0, stream>>>(theta, phiT, gT, ov);
    outproj_naive<<<dim3(16384), dim3(256), 0, stream>>>(ov, wo, bo, x, (float*)d_out);
}

// Round 12
// 371.610 us; speedup vs baseline: 11.6141x; 1.7472x over previous
//
#include <hip/hip_runtime.h>

#define B_  4
#define C_  256
#define N_  4096
#define C8_ 32
#define C2_ 128

typedef unsigned int uint32;
typedef __bf16 bf16x8 __attribute__((ext_vector_type(8)));
typedef float f32x4 __attribute__((ext_vector_type(4)));

// ---------------------------------------------------------------------------
// dst[b][o][n] = bias[o] + sum_c w[o][c] * x[b][c][n]      (naive, f32)
// (verified round 5/6/11)
// ---------------------------------------------------------------------------
__global__ __launch_bounds__(256) void lin_naive(
    const float* __restrict__ x, const float* __restrict__ w,
    const float* __restrict__ bias, float* __restrict__ dst, int OC) {
    long idx = (long)blockIdx.x * 256 + threadIdx.x;
    long total = (long)B_ * OC * N_;
    if (idx >= total) return;
    int n = (int)(idx & (N_ - 1));
    int o = (int)((idx >> 12) % OC);
    int b = (int)(idx / ((long)OC * N_));
    float acc = bias[o];
    const float* xb = x + (long)b * C_ * N_ + n;
    const float* wr = w + (long)o * C_;
    for (int c = 0; c < C_; ++c) acc += wr[c] * xb[(long)c * N_];
    dst[idx] = acc;
}

// ---------------------------------------------------------------------------
// Elementwise cast g f32 [b][c][n] -> gT bf16. grid 2048 (verified round 11).
// ---------------------------------------------------------------------------
__global__ __launch_bounds__(256) void cast_g(
    const float* __restrict__ g, __bf16* __restrict__ gT) {
    long i = ((long)blockIdx.x * 256 + threadIdx.x) * 4;
    const float4 v = *(const float4*)&g[i];
    gT[i + 0] = (__bf16)v.x;
    gT[i + 1] = (__bf16)v.y;
    gT[i + 2] = (__bf16)v.z;
    gT[i + 3] = (__bf16)v.w;
}

// ---------------------------------------------------------------------------
// Cast w_o f32 [256][128] -> bf16. 32768 elems = 32 blocks x 256 x 4.
// ---------------------------------------------------------------------------
__global__ __launch_bounds__(256) void cast_wo(
    const float* __restrict__ wo, __bf16* __restrict__ woB) {
    int i = (blockIdx.x * 256 + threadIdx.x) * 4;
    const float4 v = *(const float4*)&wo[i];
    woB[i + 0] = (__bf16)v.x;
    woB[i + 1] = (__bf16)v.y;
    woB[i + 2] = (__bf16)v.z;
    woB[i + 3] = (__bf16)v.w;
}

// ---------------------------------------------------------------------------
// Transpose phi f32 [b][32][N] -> phiT bf16 [b][N][32] (verified round 11)
// ---------------------------------------------------------------------------
__global__ __launch_bounds__(256) void transp_phi(
    const float* __restrict__ phi, __bf16* __restrict__ phiT) {
    __shared__ float tile[32][33];
    const int b  = blockIdx.y;
    const int n0 = blockIdx.x * 32;
    const int tx = threadIdx.x & 31;
    const int ty = threadIdx.x >> 5;          // 0..7
#pragma unroll
    for (int i = 0; i < 32; i += 8)
        tile[ty + i][tx] = phi[((long)b * C8_ + ty + i) * N_ + n0 + tx];
    __syncthreads();
#pragma unroll
    for (int i = 0; i < 32; i += 8)
        phiT[((long)b * N_ + n0 + ty + i) * C8_ + tx] = (__bf16)tile[tx][ty + i];
}

// ---------------------------------------------------------------------------
// MFMA flash attention (verified round 11; only change: out_v stored bf16).
// grid (128, 4), 128 threads (2 waves). Wave w owns q-rows n0+w*16 .. +15.
// Fragment layouts (mfma_f32_16x16x32_bf16), HW-verified round 11:
//   A: row=l&15, k=(l>>4)*8+j  |  B: col=l&15, k=(l>>4)*8+j
//   C/D: col=l&15, row=(l>>4)*4+reg
// ---------------------------------------------------------------------------
__global__ __launch_bounds__(128, 2) void mfma_flash(
    const float* __restrict__ theta_t, const __bf16* __restrict__ phiT,
    const __bf16* __restrict__ gT, __bf16* __restrict__ out_v) {
    __shared__ __align__(16) __bf16 phT[128 * 40];   // [m][o pad40]
    __shared__ __align__(16) __bf16 vT[128 * 136];   // [c][m pad136]
    __shared__ __align__(16) __bf16 pls[32 * 136];   // [n][m pad136]

    const int t   = threadIdx.x;
    const int b   = blockIdx.y;
    const int n0  = blockIdx.x * 32;
    const int w   = t >> 6;          // wave 0/1
    const int l   = t & 63;
    const int l15 = l & 15;
    const int lq  = l >> 4;          // 0..3

    bf16x8 aq;
#pragma unroll
    for (int j = 0; j < 8; ++j)
        aq[j] = (__bf16)theta_t[(size_t)(b * C8_ + lq * 8 + j) * N_ + n0 + w * 16 + l15];

    f32x4 acc[8];
#pragma unroll
    for (int cf = 0; cf < 8; ++cf) acc[cf] = (f32x4){0.f, 0.f, 0.f, 0.f};
    float mx[4], ln[4];
#pragma unroll
    for (int r = 0; r < 4; ++r) { mx[r] = -1e30f; ln[r] = 0.f; }

    const f32x4 zero = {0.f, 0.f, 0.f, 0.f};

    for (int mt = 0; mt < N_; mt += 128) {
        __syncthreads();
        {   // stage phT: thread t -> key row m=t (32 bf16 = 4×uint4)
            const uint4* src = (const uint4*)&phiT[((size_t)b * N_ + mt + t) * C8_];
            uint4* dst = (uint4*)&phT[t * 40];
#pragma unroll
            for (int j = 0; j < 4; ++j) dst[j] = src[j];
        }
        {   // stage vT: thread t -> channel row c=t (128 bf16 = 16×uint4)
            const uint4* src = (const uint4*)&gT[((size_t)b * C2_ + t) * N_ + mt];
            uint4* dst = (uint4*)&vT[t * 136];
#pragma unroll
            for (int j = 0; j < 16; ++j) dst[j] = src[j];
        }
        __syncthreads();

        // ---- QK: scores strip [16 n][128 m] = 8 mfma ----
        f32x4 s[8];
#pragma unroll
        for (int mf = 0; mf < 8; ++mf) {
            bf16x8 bk = *(const bf16x8*)&phT[(mf * 16 + l15) * 40 + lq * 8];
            s[mf] = __builtin_amdgcn_mfma_f32_16x16x32_bf16(aq, bk, zero, 0, 0, 0);
        }

        // ---- online softmax ----
        float rm[4], nm[4], scl[4], rs[4];
#pragma unroll
        for (int r = 0; r < 4; ++r) {
            rm[r] = s[0][r];
#pragma unroll
            for (int mf = 1; mf < 8; ++mf) rm[r] = fmaxf(rm[r], s[mf][r]);
        }
#pragma unroll
        for (int off = 8; off >= 1; off >>= 1)
#pragma unroll
            for (int r = 0; r < 4; ++r)
                rm[r] = fmaxf(rm[r], __shfl_xor(rm[r], off));
#pragma unroll
        for (int r = 0; r < 4; ++r) {
            nm[r]  = fmaxf(mx[r], rm[r]);
            scl[r] = __expf(mx[r] - nm[r]);
            rs[r]  = 0.f;
        }
#pragma unroll
        for (int mf = 0; mf < 8; ++mf)
#pragma unroll
            for (int r = 0; r < 4; ++r) {
                float p = __expf(s[mf][r] - nm[r]);
                s[mf][r] = p;
                rs[r] += p;
            }
#pragma unroll
        for (int off = 8; off >= 1; off >>= 1)
#pragma unroll
            for (int r = 0; r < 4; ++r)
                rs[r] += __shfl_xor(rs[r], off);
#pragma unroll
        for (int r = 0; r < 4; ++r) {
            ln[r] = ln[r] * scl[r] + rs[r];
            mx[r] = nm[r];
        }

        // ---- P -> LDS bf16 ----
#pragma unroll
        for (int mf = 0; mf < 8; ++mf)
#pragma unroll
            for (int r = 0; r < 4; ++r)
                pls[(w * 16 + lq * 4 + r) * 136 + mf * 16 + l15] = (__bf16)s[mf][r];
        __syncthreads();

        // ---- rescale + PV ----
#pragma unroll
        for (int cf = 0; cf < 8; ++cf)
#pragma unroll
            for (int r = 0; r < 4; ++r) acc[cf][r] *= scl[r];
#pragma unroll
        for (int ms = 0; ms < 4; ++ms) {
            bf16x8 ap = *(const bf16x8*)&pls[(w * 16 + l15) * 136 + ms * 32 + lq * 8];
#pragma unroll
            for (int cf = 0; cf < 8; ++cf) {
                bf16x8 bv = *(const bf16x8*)&vT[(cf * 16 + l15) * 136 + ms * 32 + lq * 8];
                acc[cf] = __builtin_amdgcn_mfma_f32_16x16x32_bf16(ap, bv, acc[cf], 0, 0, 0);
            }
        }
    }

    // ---- write out_v [b][n][c] bf16 ----
    float inv[4];
#pragma unroll
    for (int r = 0; r < 4; ++r) inv[r] = 1.0f / ln[r];
#pragma unroll
    for (int cf = 0; cf < 8; ++cf)
#pragma unroll
        for (int r = 0; r < 4; ++r)
            out_v[((size_t)b * N_ + n0 + w * 16 + lq * 4 + r) * C2_ + cf * 16 + l15] =
                (__bf16)(acc[cf][r] * inv[r]);
}

// ---------------------------------------------------------------------------
// MFMA outproj: out[b][o][n] = bo[o] + sum_c woB[o][c]*ovB[b][n][c] + x[b][o][n]
// grid (64, 4), 256 threads = 4 waves. Wave w owns o-strip [w*64, w*64+64).
// Block owns n-strip [bx*64, bx*64+64). K = 128 channels = 4 k-steps.
// No LDS, no syncs: A-frags (w_o) hoisted to regs, B-frags L1-cached.
// ---------------------------------------------------------------------------
__global__ __launch_bounds__(256) void outproj_mfma(
    const __bf16* __restrict__ ovB, const __bf16* __restrict__ woB,
    const float* __restrict__ bo, const float* __restrict__ x,
    float* __restrict__ out) {
    const int t   = threadIdx.x;
    const int b   = blockIdx.y;
    const int n0  = blockIdx.x * 64;
    const int w   = t >> 6;
    const int l   = t & 63;
    const int l15 = l & 15;
    const int lq  = l >> 4;
    const int o0  = w * 64;

    // hoist A-frags: afr[ot][ks] = w_o rows o0+ot*16+l15, k = ks*32+lq*8..+7
    bf16x8 afr[4][4];
#pragma unroll
    for (int ot = 0; ot < 4; ++ot)
#pragma unroll
        for (int ks = 0; ks < 4; ++ks)
            afr[ot][ks] = *(const bf16x8*)&woB[(o0 + ot * 16 + l15) * C2_ + ks * 32 + lq * 8];

#pragma unroll
    for (int nt = 0; nt < 4; ++nt) {
        f32x4 acc[4];
#pragma unroll
        for (int ot = 0; ot < 4; ++ot) acc[ot] = (f32x4){0.f, 0.f, 0.f, 0.f};
#pragma unroll
        for (int ks = 0; ks < 4; ++ks) {
            bf16x8 bfr = *(const bf16x8*)&ovB[((size_t)b * N_ + n0 + nt * 16 + l15) * C2_ + ks * 32 + lq * 8];
#pragma unroll
            for (int ot = 0; ot < 4; ++ot)
                acc[ot] = __builtin_amdgcn_mfma_f32_16x16x32_bf16(afr[ot][ks], bfr, acc[ot], 0, 0, 0);
        }
#pragma unroll
        for (int ot = 0; ot < 4; ++ot)
#pragma unroll
            for (int r = 0; r < 4; ++r) {
                int o = o0 + ot * 16 + lq * 4 + r;
                size_t idx = ((size_t)b * C_ + o) * N_ + n0 + nt * 16 + l15;
                out[idx] = acc[ot][r] + bo[o] + x[idx];
            }
    }
}

// ---------------------------------------------------------------------------
extern "C" void kernel_launch(void* const* d_in, const int* in_sizes, int n_in,
                              void* d_out, int out_size, void* d_ws, size_t ws_size,
                              hipStream_t stream) {
    const float* x  = (const float*)d_in[0];
    const float* wt = (const float*)d_in[1];
    const float* bt = (const float*)d_in[2];
    const float* wp = (const float*)d_in[3];
    const float* bp = (const float*)d_in[4];
    const float* wg = (const float*)d_in[5];
    const float* bg = (const float*)d_in[6];
    const float* wo = (const float*)d_in[7];
    const float* bo = (const float*)d_in[8];

    // ws: theta 2MB | phi 2MB | ovB bf16 4MB | woB 64KB = 8.07 MB (< 12 proven-safe)
    char* ws = (char*)d_ws;
    float*  theta = (float*)(ws);
    float*  phi   = (float*)(ws + (2u << 20));
    __bf16* ovB   = (__bf16*)(ws + (4u << 20));
    __bf16* woB   = (__bf16*)(ws + (8u << 20));
    // d_out scratch (all dead before outproj_mfma overwrites d_out):
    //   g f32 [b][128][N] 8MB | gT bf16 4MB | phiT bf16 1MB
    float*  g    = (float*)d_out;
    __bf16* gT   = (__bf16*)((char*)d_out + (8u << 20));
    __bf16* phiT = (__bf16*)((char*)d_out + (12u << 20));

    lin_naive<<<dim3(2048), dim3(256), 0, stream>>>(x, wt, bt, theta, 32);
    lin_naive<<<dim3(2048), dim3(256), 0, stream>>>(x, wp, bp, phi, 32);
    lin_naive<<<dim3(8192), dim3(256), 0, stream>>>(x, wg, bg, g, 128);
    cast_g<<<dim3(2048), dim3(256), 0, stream>>>(g, gT);
    cast_wo<<<dim3(32), dim3(256), 0, stream>>>(wo, woB);
    transp_phi<<<dim3(128, 4), dim3(256), 0, stream>>>(phi, phiT);
    mfma_flash<<<dim3(128, 4), dim3(128), 0, stream>>>(theta, phiT, gT, ovB);
    outproj_mfma<<<dim3(64, 4), dim3(256), 0, stream>>>(ovB, woB, bo, x, (float*)d_out);
}

// Round 13
// 208.543 us; speedup vs baseline: 20.6955x; 1.7819x over previous
//
#include <hip/hip_runtime.h>

#define B_  4
#define C_  256
#define N_  4096
#define C8_ 32
#define C2_ 128

typedef unsigned int uint32;
typedef __bf16 bf16x8 __attribute__((ext_vector_type(8)));
typedef float f32x4 __attribute__((ext_vector_type(4)));

// ---------------------------------------------------------------------------
// Pack w_theta/w_phi/w_g -> bf16 w_allB [192][256] + f32 b_all [192]
// rows 0-31 theta, 32-63 phi, 64-191 g. 1 elem/thread, trivial indexing.
// ---------------------------------------------------------------------------
__global__ __launch_bounds__(256) void pack_wB(
    const float* __restrict__ wt, const float* __restrict__ bt,
    const float* __restrict__ wp, const float* __restrict__ bp,
    const float* __restrict__ wg, const float* __restrict__ bg,
    __bf16* __restrict__ w_allB, float* __restrict__ b_all) {
    int i = blockIdx.x * 256 + threadIdx.x;   // grid 192 -> i < 49152
    int o = i >> 8, c = i & 255;
    float v;
    if (o < 32)      v = wt[o * 256 + c];
    else if (o < 64) v = wp[(o - 32) * 256 + c];
    else             v = wg[(o - 64) * 256 + c];
    w_allB[i] = (__bf16)v;
    if (i < 192) {
        float bv;
        if (i < 32)      bv = bt[i];
        else if (i < 64) bv = bp[i - 32];
        else             bv = bg[i - 64];
        b_all[i] = bv;
    }
}

// ---------------------------------------------------------------------------
// Cast w_o f32 [256][128] -> bf16 (verified round 12). grid 32.
// ---------------------------------------------------------------------------
__global__ __launch_bounds__(256) void cast_wo(
    const float* __restrict__ wo, __bf16* __restrict__ woB) {
    int i = (blockIdx.x * 256 + threadIdx.x) * 4;
    const float4 v = *(const float4*)&wo[i];
    woB[i + 0] = (__bf16)v.x;
    woB[i + 1] = (__bf16)v.y;
    woB[i + 2] = (__bf16)v.z;
    woB[i + 3] = (__bf16)v.w;
}

// ---------------------------------------------------------------------------
// Transpose x f32 [b][c][n] -> xT bf16 [b][n][c]
// (structural clone of verified transp_phi; c blocked by 32)
// grid (128, 8, 4), 256 threads.
// ---------------------------------------------------------------------------
__global__ __launch_bounds__(256) void transp_x(
    const float* __restrict__ x, __bf16* __restrict__ xT) {
    __shared__ float tile[32][33];
    const int b  = blockIdx.z;
    const int c0 = blockIdx.y * 32;
    const int n0 = blockIdx.x * 32;
    const int tx = threadIdx.x & 31;
    const int ty = threadIdx.x >> 5;          // 0..7
#pragma unroll
    for (int i = 0; i < 32; i += 8)
        tile[ty + i][tx] = x[((long)b * C_ + c0 + ty + i) * N_ + n0 + tx];
    __syncthreads();
#pragma unroll
    for (int i = 0; i < 32; i += 8)
        xT[((long)b * N_ + n0 + ty + i) * C_ + c0 + tx] = (__bf16)tile[tx][ty + i];
}

// ---------------------------------------------------------------------------
// MFMA projections: [192 o][256 c] x [c][16 n per wave] per wave.
// grid (64, 4), 256 threads = 4 waves, no LDS. Wave w: n-tile n0+w*16.
// theta f32 [b][32][N]; phiT bf16 [b][N][32]; gT bf16 [b][128][N]; + bias.
// Fragment layouts HW-verified rounds 11/12.
// ---------------------------------------------------------------------------
__global__ __launch_bounds__(256) void proj_mfma(
    const __bf16* __restrict__ xT, const __bf16* __restrict__ w_allB,
    const float* __restrict__ b_all, float* __restrict__ theta,
    __bf16* __restrict__ phiT, __bf16* __restrict__ gT) {
    const int t   = threadIdx.x;
    const int b   = blockIdx.y;
    const int wn  = t >> 6;          // wave 0..3
    const int n0  = blockIdx.x * 64 + wn * 16;
    const int l   = t & 63;
    const int l15 = l & 15;
    const int lq  = l >> 4;          // 0..3
    const int gn  = n0 + l15;        // this lane's n column (D col)

    f32x4 acc[12];
#pragma unroll
    for (int ot = 0; ot < 12; ++ot) acc[ot] = (f32x4){0.f, 0.f, 0.f, 0.f};

#pragma unroll
    for (int ks = 0; ks < 8; ++ks) {
        const bf16x8 bfr = *(const bf16x8*)&xT[((size_t)b * N_ + gn) * C_ + ks * 32 + lq * 8];
#pragma unroll
        for (int ot = 0; ot < 12; ++ot) {
            const bf16x8 afr = *(const bf16x8*)&w_allB[(ot * 16 + l15) * C_ + ks * 32 + lq * 8];
            acc[ot] = __builtin_amdgcn_mfma_f32_16x16x32_bf16(afr, bfr, acc[ot], 0, 0, 0);
        }
    }

    // epilogue: D[col=l15 -> n][row=lq*4+r -> o] + bias, scatter by o-range
#pragma unroll
    for (int ot = 0; ot < 12; ++ot)
#pragma unroll
        for (int r = 0; r < 4; ++r) {
            const int o = ot * 16 + lq * 4 + r;
            const float v = acc[ot][r] + b_all[o];
            if (o < 32)
                theta[((size_t)b * C8_ + o) * N_ + gn] = v;
            else if (o < 64)
                phiT[((size_t)b * N_ + gn) * C8_ + (o - 32)] = (__bf16)v;
            else
                gT[((size_t)b * C2_ + (o - 64)) * N_ + gn] = (__bf16)v;
        }
}

// ---------------------------------------------------------------------------
// MFMA flash attention (verified rounds 11/12). grid (128,4), 128 thr, 2 waves.
// ---------------------------------------------------------------------------
__global__ __launch_bounds__(128, 2) void mfma_flash(
    const float* __restrict__ theta_t, const __bf16* __restrict__ phiT,
    const __bf16* __restrict__ gT, __bf16* __restrict__ out_v) {
    __shared__ __align__(16) __bf16 phT[128 * 40];   // [m][o pad40]
    __shared__ __align__(16) __bf16 vT[128 * 136];   // [c][m pad136]
    __shared__ __align__(16) __bf16 pls[32 * 136];   // [n][m pad136]

    const int t   = threadIdx.x;
    const int b   = blockIdx.y;
    const int n0  = blockIdx.x * 32;
    const int w   = t >> 6;          // wave 0/1
    const int l   = t & 63;
    const int l15 = l & 15;
    const int lq  = l >> 4;          // 0..3

    bf16x8 aq;
#pragma unroll
    for (int j = 0; j < 8; ++j)
        aq[j] = (__bf16)theta_t[(size_t)(b * C8_ + lq * 8 + j) * N_ + n0 + w * 16 + l15];

    f32x4 acc[8];
#pragma unroll
    for (int cf = 0; cf < 8; ++cf) acc[cf] = (f32x4){0.f, 0.f, 0.f, 0.f};
    float mx[4], ln[4];
#pragma unroll
    for (int r = 0; r < 4; ++r) { mx[r] = -1e30f; ln[r] = 0.f; }

    const f32x4 zero = {0.f, 0.f, 0.f, 0.f};

    for (int mt = 0; mt < N_; mt += 128) {
        __syncthreads();
        {   // stage phT
            const uint4* src = (const uint4*)&phiT[((size_t)b * N_ + mt + t) * C8_];
            uint4* dst = (uint4*)&phT[t * 40];
#pragma unroll
            for (int j = 0; j < 4; ++j) dst[j] = src[j];
        }
        {   // stage vT
            const uint4* src = (const uint4*)&gT[((size_t)b * C2_ + t) * N_ + mt];
            uint4* dst = (uint4*)&vT[t * 136];
#pragma unroll
            for (int j = 0; j < 16; ++j) dst[j] = src[j];
        }
        __syncthreads();

        // QK
        f32x4 s[8];
#pragma unroll
        for (int mf = 0; mf < 8; ++mf) {
            bf16x8 bk = *(const bf16x8*)&phT[(mf * 16 + l15) * 40 + lq * 8];
            s[mf] = __builtin_amdgcn_mfma_f32_16x16x32_bf16(aq, bk, zero, 0, 0, 0);
        }

        // online softmax
        float rm[4], nm[4], scl[4], rs[4];
#pragma unroll
        for (int r = 0; r < 4; ++r) {
            rm[r] = s[0][r];
#pragma unroll
            for (int mf = 1; mf < 8; ++mf) rm[r] = fmaxf(rm[r], s[mf][r]);
        }
#pragma unroll
        for (int off = 8; off >= 1; off >>= 1)
#pragma unroll
            for (int r = 0; r < 4; ++r)
                rm[r] = fmaxf(rm[r], __shfl_xor(rm[r], off));
#pragma unroll
        for (int r = 0; r < 4; ++r) {
            nm[r]  = fmaxf(mx[r], rm[r]);
            scl[r] = __expf(mx[r] - nm[r]);
            rs[r]  = 0.f;
        }
#pragma unroll
        for (int mf = 0; mf < 8; ++mf)
#pragma unroll
            for (int r = 0; r < 4; ++r) {
                float p = __expf(s[mf][r] - nm[r]);
                s[mf][r] = p;
                rs[r] += p;
            }
#pragma unroll
        for (int off = 8; off >= 1; off >>= 1)
#pragma unroll
            for (int r = 0; r < 4; ++r)
                rs[r] += __shfl_xor(rs[r], off);
#pragma unroll
        for (int r = 0; r < 4; ++r) {
            ln[r] = ln[r] * scl[r] + rs[r];
            mx[r] = nm[r];
        }

        // P -> LDS bf16
#pragma unroll
        for (int mf = 0; mf < 8; ++mf)
#pragma unroll
            for (int r = 0; r < 4; ++r)
                pls[(w * 16 + lq * 4 + r) * 136 + mf * 16 + l15] = (__bf16)s[mf][r];
        __syncthreads();

        // rescale + PV
#pragma unroll
        for (int cf = 0; cf < 8; ++cf)
#pragma unroll
            for (int r = 0; r < 4; ++r) acc[cf][r] *= scl[r];
#pragma unroll
        for (int ms = 0; ms < 4; ++ms) {
            bf16x8 ap = *(const bf16x8*)&pls[(w * 16 + l15) * 136 + ms * 32 + lq * 8];
#pragma unroll
            for (int cf = 0; cf < 8; ++cf) {
                bf16x8 bv = *(const bf16x8*)&vT[(cf * 16 + l15) * 136 + ms * 32 + lq * 8];
                acc[cf] = __builtin_amdgcn_mfma_f32_16x16x32_bf16(ap, bv, acc[cf], 0, 0, 0);
            }
        }
    }

    float inv[4];
#pragma unroll
    for (int r = 0; r < 4; ++r) inv[r] = 1.0f / ln[r];
#pragma unroll
    for (int cf = 0; cf < 8; ++cf)
#pragma unroll
        for (int r = 0; r < 4; ++r)
            out_v[((size_t)b * N_ + n0 + w * 16 + lq * 4 + r) * C2_ + cf * 16 + l15] =
                (__bf16)(acc[cf][r] * inv[r]);
}

// ---------------------------------------------------------------------------
// MFMA outproj (verified round 12). grid (64,4), 256 threads.
// ---------------------------------------------------------------------------
__global__ __launch_bounds__(256) void outproj_mfma(
    const __bf16* __restrict__ ovB, const __bf16* __restrict__ woB,
    const float* __restrict__ bo, const float* __restrict__ x,
    float* __restrict__ out) {
    const int t   = threadIdx.x;
    const int b   = blockIdx.y;
    const int n0  = blockIdx.x * 64;
    const int w   = t >> 6;
    const int l   = t & 63;
    const int l15 = l & 15;
    const int lq  = l >> 4;
    const int o0  = w * 64;

    bf16x8 afr[4][4];
#pragma unroll
    for (int ot = 0; ot < 4; ++ot)
#pragma unroll
        for (int ks = 0; ks < 4; ++ks)
            afr[ot][ks] = *(const bf16x8*)&woB[(o0 + ot * 16 + l15) * C2_ + ks * 32 + lq * 8];

#pragma unroll
    for (int nt = 0; nt < 4; ++nt) {
        f32x4 acc[4];
#pragma unroll
        for (int ot = 0; ot < 4; ++ot) acc[ot] = (f32x4){0.f, 0.f, 0.f, 0.f};
#pragma unroll
        for (int ks = 0; ks < 4; ++ks) {
            bf16x8 bfr = *(const bf16x8*)&ovB[((size_t)b * N_ + n0 + nt * 16 + l15) * C2_ + ks * 32 + lq * 8];
#pragma unroll
            for (int ot = 0; ot < 4; ++ot)
                acc[ot] = __builtin_amdgcn_mfma_f32_16x16x32_bf16(afr[ot][ks], bfr, acc[ot], 0, 0, 0);
        }
#pragma unroll
        for (int ot = 0; ot < 4; ++ot)
#pragma unroll
            for (int r = 0; r < 4; ++r) {
                int o = o0 + ot * 16 + lq * 4 + r;
                size_t idx = ((size_t)b * C_ + o) * N_ + n0 + nt * 16 + l15;
                out[idx] = acc[ot][r] + bo[o] + x[idx];
            }
    }
}

// ---------------------------------------------------------------------------
extern "C" void kernel_launch(void* const* d_in, const int* in_sizes, int n_in,
                              void* d_out, int out_size, void* d_ws, size_t ws_size,
                              hipStream_t stream) {
    const float* x  = (const float*)d_in[0];
    const float* wt = (const float*)d_in[1];
    const float* bt = (const float*)d_in[2];
    const float* wp = (const float*)d_in[3];
    const float* bp = (const float*)d_in[4];
    const float* wg = (const float*)d_in[5];
    const float* bg = (const float*)d_in[6];
    const float* wo = (const float*)d_in[7];
    const float* bo = (const float*)d_in[8];

    // ws (7.3 MB < 12 proven-safe):
    //   theta f32 2MB | phiT bf16 1MB | ovB bf16 4MB | woB 64KB | w_allB 96KB | b_all 768B
    char* ws = (char*)d_ws;
    float*  theta  = (float*)(ws);
    __bf16* phiT   = (__bf16*)(ws + (2u << 20));
    __bf16* ovB    = (__bf16*)(ws + (3u << 20));
    __bf16* woB    = (__bf16*)(ws + (7u << 20));
    __bf16* w_allB = (__bf16*)(ws + (7u << 20) + (64u << 10));
    float*  b_all  = (float*)(ws + (7u << 20) + (160u << 10));
    // d_out scratch (dead before outproj_mfma writes):
    //   xT bf16 [b][n][c] 8MB | gT bf16 [b][c][n] 4MB
    __bf16* xT = (__bf16*)d_out;
    __bf16* gT = (__bf16*)((char*)d_out + (8u << 20));

    pack_wB<<<dim3(192), dim3(256), 0, stream>>>(wt, bt, wp, bp, wg, bg, w_allB, b_all);
    cast_wo<<<dim3(32), dim3(256), 0, stream>>>(wo, woB);
    transp_x<<<dim3(128, 8, 4), dim3(256), 0, stream>>>(x, xT);
    proj_mfma<<<dim3(64, 4), dim3(256), 0, stream>>>(xT, w_allB, b_all, theta, phiT, gT);
    mfma_flash<<<dim3(128, 4), dim3(128), 0, stream>>>(theta, phiT, gT, ovB);
    outproj_mfma<<<dim3(64, 4), dim3(256), 0, stream>>>(ovB, woB, bo, x, (float*)d_out);
}